// Round 1
// baseline (194.546 us; speedup 1.0000x reference)
//
#include <hip/hip_runtime.h>

// shifts: out[b, o*C + c, h, w] = x[b, c, h - sx, w - sy]  (zero outside bounds)
// offsets order: (0,0), then (sx,sy) for sx in {-1,0,1}, sy in {-1,0,1}, skip (0,0)
// Shapes: x [16, 32, 192, 192] f32 -> out [16, 288, 192, 192] f32

constexpr int B  = 16;
constexpr int C  = 32;
constexpr int H  = 192;
constexpr int W  = 192;
constexpr int O  = 9;
constexpr int OC = O * C;            // 288
constexpr int W4 = W / 4;            // 48 float4 per row
constexpr int PLANE4 = H * W4;       // 9216 float4 per (b, oc) plane
constexpr int BLK = 256;
constexpr int BLKS_PER_PLANE = PLANE4 / BLK;  // 36 (exact)

__global__ __launch_bounds__(BLK) void shifts_kernel(const float* __restrict__ x,
                                                     float4* __restrict__ out) {
    const int oc = blockIdx.y;       // output channel: o*C + c
    const int b  = blockIdx.z;
    const int o  = oc / C;           // offset index 0..8 (block-uniform)
    const int c  = oc - o * C;

    // decode (sx, sy): o=0 -> (0,0); else index into 3x3 grid skipping center
    int sx = 0, sy = 0;
    if (o != 0) {
        int j = o - 1;
        j += (j >= 4);               // skip the (0,0) slot at grid index 4
        sx = j / 3 - 1;
        sy = j - (j / 3) * 3 - 1;
    }

    const int i  = blockIdx.x * BLK + threadIdx.x;   // [0, PLANE4)
    const int w4 = i % W4;
    const int h  = i / W4;

    const int r = h - sx;            // source row
    float4 v = make_float4(0.f, 0.f, 0.f, 0.f);
    if ((unsigned)r < (unsigned)H) { // wave-uniform (h uniform per 48-lane run, sx block-uniform)
        const float* __restrict__ src = x + (size_t)((b * C + c) * H + r) * W;
        const int w0 = 4 * w4 - sy;  // source col of element 0
        float vals[4];
#pragma unroll
        for (int k = 0; k < 4; ++k) {
            const int col = w0 + k;
            vals[k] = ((unsigned)col < (unsigned)W) ? src[col] : 0.f;
        }
        v = make_float4(vals[0], vals[1], vals[2], vals[3]);
    }
    out[(size_t)(b * OC + oc) * PLANE4 + i] = v;     // coalesced float4 store
}

extern "C" void kernel_launch(void* const* d_in, const int* in_sizes, int n_in,
                              void* d_out, int out_size, void* d_ws, size_t ws_size,
                              hipStream_t stream) {
    const float* x = (const float*)d_in[0];
    float4* out = (float4*)d_out;
    dim3 grid(BLKS_PER_PLANE, OC, B);   // (36, 288, 16)
    dim3 block(BLK);
    shifts_kernel<<<grid, block, 0, stream>>>(x, out);
}

// Round 2
// 141.124 us; speedup vs baseline: 1.3785x; 1.3785x over previous
//
#include <hip/hip_runtime.h>

// shifts: out[b, o*C + c, h, w] = x[b, c, h - sx, w - sy]  (zero outside bounds)
// offset order o=0..8: (0,0), then (sx,sy) nested loop over {-1,0,1}^2 skipping (0,0)
//   o=1:(-1,-1) o=2:(-1,0) o=3:(-1,1) o=4:(0,-1) o=5:(0,1) o=6:(1,-1) o=7:(1,0) o=8:(1,1)
//
// Input-centric scatter: each thread owns one aligned float4 of x (read ONCE from
// HBM), builds the 3 column-shifted variants in registers, and writes 9 aligned
// coalesced float4 stores (one per offset). This avoids the round-1 problem where
// the 680 MB write stream evicted the input from L3 between its 9 re-reads
// (round 1: ~1.36 GB HBM traffic -> 194 us; ideal is 755 MB -> ~111 us).

constexpr int B  = 16;
constexpr int C  = 32;
constexpr int H  = 192;
constexpr int W  = 192;
constexpr int OC = 9 * C;              // 288
constexpr int W4 = W / 4;              // 48 float4 per row
constexpr int PLANE4   = H * W4;       // 9216 float4 per (channel) plane
constexpr int OSTRIDE4 = C * PLANE4;   // float4 stride between offset groups
constexpr int TOTAL4   = B * C * H * W4;  // 4,718,592 input float4s
constexpr int BLK = 256;

__global__ __launch_bounds__(BLK) void shifts_scatter(const float* __restrict__ x,
                                                      float4* __restrict__ out) {
    const int i = blockIdx.x * BLK + threadIdx.x;   // input float4 index (grid exact)
    const int w4 = i % W4;
    int t = i / W4;
    const int g = t % H;        // input row
    t /= H;
    const int c = t % C;
    const int b = t / C;

    const float4* __restrict__ x4 = (const float4*)x;
    const float4 cur = x4[i];
    // neighbor scalars for the +/-1 column shifts (L1 hits; same lines as cur)
    const size_t xoff = (size_t)i * 4;
    const float prevw = (w4 > 0)      ? x[xoff - 1] : 0.f;   // col 4*w4 - 1
    const float nextx = (w4 < W4 - 1) ? x[xoff + 4] : 0.f;   // col 4*w4 + 4

    // shifted variants: out col block [4w4,4w4+3] needs input cols [4w4-sy, 4w4+3-sy]
    const float4 vL = make_float4(prevw, cur.x, cur.y, cur.z);  // sy = +1
    const float4 vR = make_float4(cur.y, cur.z, cur.w, nextx);  // sy = -1

    // out index (float4 units): ((b*OC + o*C + c) * H + h) * W4 + w4
    float4* const base = out + ((size_t)(b * OC + c)) * PLANE4 + (size_t)g * W4 + w4;

    // o = 0: (0,0)
    base[0] = cur;

#pragma unroll
    for (int o = 1; o < 9; ++o) {
        int j = o - 1;
        j += (j >= 4);                        // skip (0,0) at 3x3 grid slot 4
        const int sx = j / 3 - 1;
        const int sy = j - (j / 3) * 3 - 1;
        const float4 v = (sy == 0) ? cur : ((sy == 1) ? vL : vR);
        const int h = g + sx;                 // destination row for this offset
        if ((unsigned)h < (unsigned)H)
            base[(ptrdiff_t)o * OSTRIDE4 + (ptrdiff_t)sx * W4] = v;
    }

    // border rows no thread scatters into: zero-fill them
    const float4 z = make_float4(0.f, 0.f, 0.f, 0.f);
    if (g == 0) {          // sx=+1 offsets (o=6,7,8): out row 0 = x(-1) = 0
        base[(ptrdiff_t)6 * OSTRIDE4] = z;
        base[(ptrdiff_t)7 * OSTRIDE4] = z;
        base[(ptrdiff_t)8 * OSTRIDE4] = z;
    }
    if (g == H - 1) {      // sx=-1 offsets (o=1,2,3): out row 191 = x(192) = 0
        base[(ptrdiff_t)1 * OSTRIDE4] = z;
        base[(ptrdiff_t)2 * OSTRIDE4] = z;
        base[(ptrdiff_t)3 * OSTRIDE4] = z;
    }
}

extern "C" void kernel_launch(void* const* d_in, const int* in_sizes, int n_in,
                              void* d_out, int out_size, void* d_ws, size_t ws_size,
                              hipStream_t stream) {
    const float* x = (const float*)d_in[0];
    float4* out = (float4*)d_out;
    shifts_scatter<<<dim3(TOTAL4 / BLK), dim3(BLK), 0, stream>>>(x, out);
}

// Round 3
// 119.257 us; speedup vs baseline: 1.6313x; 1.1834x over previous
//
#include <hip/hip_runtime.h>

// shifts: out[b, o*C + c, h, w] = x[b, c, h - sx, w - sy]  (zero outside bounds)
// offset order o=0..8: (0,0), then (sx,sy) nested over {-1,0,1}^2 skipping (0,0)
//
// Round 2 (input-centric scatter, read x once): 141.1 us = 5.35 TB/s effective.
// Round 3 delta (ONE variable): nontemporal output stores. Output is 680 MB
// write-only; plain stores write-allocate in 32 MB L2 -> pure churn. nt flag
// streams them to HBM. Loads stay cached (neighbor scalars rely on L1).

using f4 = __attribute__((ext_vector_type(4))) float;

constexpr int B  = 16;
constexpr int C  = 32;
constexpr int H  = 192;
constexpr int W  = 192;
constexpr int OC = 9 * C;              // 288
constexpr int W4 = W / 4;              // 48 float4 per row
constexpr int PLANE4   = H * W4;       // 9216 float4 per channel plane
constexpr int OSTRIDE4 = C * PLANE4;   // float4 stride between offset groups
constexpr int TOTAL4   = B * C * H * W4;  // 4,718,592 input float4s
constexpr int BLK = 256;

__global__ __launch_bounds__(BLK) void shifts_scatter_nt(const float* __restrict__ x,
                                                         f4* __restrict__ out) {
    const int i = blockIdx.x * BLK + threadIdx.x;   // input float4 index (grid exact)
    const int w4 = i % W4;
    int t = i / W4;
    const int g = t % H;        // input row
    t /= H;
    const int c = t % C;
    const int b = t / C;

    const f4* __restrict__ x4 = (const f4*)x;
    const f4 cur = x4[i];
    // neighbor scalars for the +/-1 column shifts (L1 hits; same lines as cur)
    const size_t xoff = (size_t)i * 4;
    const float prevw = (w4 > 0)      ? x[xoff - 1] : 0.f;   // col 4*w4 - 1
    const float nextx = (w4 < W4 - 1) ? x[xoff + 4] : 0.f;   // col 4*w4 + 4

    const f4 vL = {prevw, cur.x, cur.y, cur.z};  // sy = +1
    const f4 vR = {cur.y, cur.z, cur.w, nextx};  // sy = -1

    // out index (float4 units): ((b*OC + o*C + c) * H + h) * W4 + w4
    f4* const base = out + ((size_t)(b * OC + c)) * PLANE4 + (size_t)g * W4 + w4;

    // o = 0: (0,0)
    __builtin_nontemporal_store(cur, base);

#pragma unroll
    for (int o = 1; o < 9; ++o) {
        int j = o - 1;
        j += (j >= 4);                        // skip (0,0) at 3x3 grid slot 4
        const int sx = j / 3 - 1;
        const int sy = j - (j / 3) * 3 - 1;
        const f4 v = (sy == 0) ? cur : ((sy == 1) ? vL : vR);
        const int h = g + sx;                 // destination row for this offset
        if ((unsigned)h < (unsigned)H)
            __builtin_nontemporal_store(v, base + (ptrdiff_t)o * OSTRIDE4 + (ptrdiff_t)sx * W4);
    }

    // border rows no thread scatters into: zero-fill
    const f4 z = {0.f, 0.f, 0.f, 0.f};
    if (g == 0) {          // sx=+1 offsets (o=6,7,8): out row 0 = 0
#pragma unroll
        for (int o = 6; o <= 8; ++o)
            __builtin_nontemporal_store(z, base + (ptrdiff_t)o * OSTRIDE4);
    }
    if (g == H - 1) {      // sx=-1 offsets (o=1,2,3): out row 191 = 0
#pragma unroll
        for (int o = 1; o <= 3; ++o)
            __builtin_nontemporal_store(z, base + (ptrdiff_t)o * OSTRIDE4);
    }
}

extern "C" void kernel_launch(void* const* d_in, const int* in_sizes, int n_in,
                              void* d_out, int out_size, void* d_ws, size_t ws_size,
                              hipStream_t stream) {
    const float* x = (const float*)d_in[0];
    f4* out = (f4*)d_out;
    shifts_scatter_nt<<<dim3(TOTAL4 / BLK), dim3(BLK), 0, stream>>>(x, out);
}